// Round 1
// baseline (271.587 us; speedup 1.0000x reference)
//
#include <hip/hip_runtime.h>

// LogicLayer: out[b,n] = sum_g gate_g(a,b) * softmax(w[n])_g
// where a = x[b, idx_a[n]], b = x[b, idx_b[n]].
// All 16 gates are bilinear in (a,b):
//   out[b,n] = C0[n] + C1[n]*a + C2[n]*b + C3[n]*a*b
// with C0..C3 fixed linear combos of the softmax probs. We precompute
// C per neuron into d_ws (16384 * float4 = 256 KB), then one workgroup
// per batch row stages the 64 KB x-row in LDS and does vectorized
// gather + bilinear eval.

#define IN_N   16384
#define OUT_N  16384

__global__ __launch_bounds__(256) void coeff_kernel(const float* __restrict__ w,
                                                    float4* __restrict__ coeff,
                                                    int nout) {
    int n = blockIdx.x * blockDim.x + threadIdx.x;
    if (n >= nout) return;
    const float* wn = w + (size_t)n * 16;
    float p[16];
    float m = -1e30f;
#pragma unroll
    for (int i = 0; i < 16; ++i) { p[i] = wn[i]; m = fmaxf(m, p[i]); }
    float s = 0.f;
#pragma unroll
    for (int i = 0; i < 16; ++i) { p[i] = __expf(p[i] - m); s += p[i]; }
    float inv = 1.f / s;
#pragma unroll
    for (int i = 0; i < 16; ++i) p[i] *= inv;
    // gate list: 0, ab, a-ab, a, b-ab, b, a+b-2ab, a+b-ab,
    //            1-a-b+ab, 1-a-b+2ab, 1-b, 1-b+ab, 1-a, 1-a+ab, 1-ab, 1
    float c0 = p[8] + p[9] + p[10] + p[11] + p[12] + p[13] + p[14] + p[15];
    float c1 = p[2] + p[3] + p[6] + p[7] - p[8] - p[9] - p[12] - p[13];
    float c2 = p[4] + p[5] + p[6] + p[7] - p[8] - p[9] - p[10] - p[11];
    float c3 = p[1] - p[2] - p[4] - 2.f * p[6] - p[7]
             + p[8] + 2.f * p[9] + p[11] + p[13] - p[14];
    coeff[n] = make_float4(c0, c1, c2, c3);
}

__global__ __launch_bounds__(512) void logic_kernel(const float* __restrict__ x,
                                                    const int* __restrict__ idx_a,
                                                    const int* __restrict__ idx_b,
                                                    const float4* __restrict__ coeff,
                                                    float* __restrict__ out) {
    __shared__ float row[IN_N];  // 64 KB: one full x-row

    const int b = blockIdx.x;
    const float4* xr4 = (const float4*)(x + (size_t)b * IN_N);
    float4* row4 = (float4*)row;
    for (int i = threadIdx.x; i < IN_N / 4; i += blockDim.x) {
        row4[i] = xr4[i];
    }
    __syncthreads();

    float4* outr4 = (float4*)(out + (size_t)b * OUT_N);
    const int4* ia4 = (const int4*)idx_a;
    const int4* ib4 = (const int4*)idx_b;

    for (int i = threadIdx.x; i < OUT_N / 4; i += blockDim.x) {
        int4 ia = ia4[i];
        int4 ib = ib4[i];
        float4 c0 = coeff[4 * i + 0];
        float4 c1 = coeff[4 * i + 1];
        float4 c2 = coeff[4 * i + 2];
        float4 c3 = coeff[4 * i + 3];
        float a0 = row[ia.x], a1 = row[ia.y], a2 = row[ia.z], a3 = row[ia.w];
        float b0 = row[ib.x], b1 = row[ib.y], b2 = row[ib.z], b3 = row[ib.w];
        float4 o;
        o.x = fmaf(a0, fmaf(c0.w, b0, c0.y), fmaf(c0.z, b0, c0.x));
        o.y = fmaf(a1, fmaf(c1.w, b1, c1.y), fmaf(c1.z, b1, c1.x));
        o.z = fmaf(a2, fmaf(c2.w, b2, c2.y), fmaf(c2.z, b2, c2.x));
        o.w = fmaf(a3, fmaf(c3.w, b3, c3.y), fmaf(c3.z, b3, c3.x));
        outr4[i] = o;
    }
}

extern "C" void kernel_launch(void* const* d_in, const int* in_sizes, int n_in,
                              void* d_out, int out_size, void* d_ws, size_t ws_size,
                              hipStream_t stream) {
    const float* x = (const float*)d_in[0];       // (B, IN) fp32
    const float* w = (const float*)d_in[1];       // (OUT, 16) fp32
    const int* idx_a = (const int*)d_in[2];       // (OUT,) int32
    const int* idx_b = (const int*)d_in[3];       // (OUT,) int32

    const int nout = in_sizes[2];                 // 16384
    const int batch = in_sizes[0] / IN_N;         // 2048

    float4* coeff = (float4*)d_ws;                // nout * 16 bytes = 256 KB

    coeff_kernel<<<(nout + 255) / 256, 256, 0, stream>>>(w, coeff, nout);
    logic_kernel<<<batch, 512, 0, stream>>>(x, idx_a, idx_b, coeff, (float*)d_out);
}